// Round 22
// baseline (77.638 us; speedup 1.0000x reference)
//
#include <hip/hip_runtime.h>
#include <math.h>

// RWKV-6 fused recurrent WKV — chunked linear scan, MFMA formulation.
// B=4, T=2048, H=16, N=64, fp32 in/out; bf16 MFMA operands, fp32 accum.
//
// R22: CHUNK-PAIRED P1. P1 is latency-bound (no pipe >36%; occupancy/staging
// position/VALU all tested) -> attack in-wave ILP: each workgroup processes
// chunks (2gp, 2gp+1) with duplicated LDS buffers; every phase stages both
// chunks then MFMAs both, so the two independent dependency chains interleave
// inside one wave. (256,2): VGPR ~165 < 256 budget; LDS 75.8KB -> 2 blocks/CU.
// Epilogue sequential per chunk (accO short-lived, R8 rule).
//
// Ledger: R8 live-range > LDS. R9 manual RNE only. R11-R14 coverage/punning
// NaNs — excluded. R15 layout serves consumer. R16 bf16-L P0 + packed k2.
// R17 prefetch-spill. R18 compose = 70.8. R19 decay-products = 67.8 (best).
// R20 occupancy null. R21 reproduced 67.5.
// Pre-commit: P1<=36 win; 38-44 neutral (revert); >=44 or spill -> revert.

namespace {
constexpr int B = 4, T = 2048, H = 16, N = 64;
constexpr int BH = B * H;
constexpr int NG = 32;           // chunks per (b,h)
constexpr int TC = 64;           // steps per chunk
constexpr int LDP = 72;          // LDS row stride (elems): 144B, 16B-aligned

typedef __attribute__((ext_vector_type(8))) short s8v;   // 8 bf16
typedef __attribute__((ext_vector_type(4))) float f4v;

#define MFMA16(a, b, c) __builtin_amdgcn_mfma_f32_16x16x32_bf16((a), (b), (c), 0, 0, 0)

__device__ __forceinline__ unsigned short cv(float f) {
    union { float f; unsigned u; } x; x.f = f;
    unsigned r = x.u + 0x7FFFu + ((x.u >> 16) & 1u);   // branchless RNE
    return (unsigned short)(r >> 16);
}

__device__ __forceinline__ float bfhi(unsigned u) {   // upper bf16 -> float
    union { unsigned u; float f; } x; x.u = u & 0xFFFF0000u; return x.f;
}
__device__ __forceinline__ float bflo(unsigned u) {   // lower bf16 -> float
    union { unsigned u; float f; } x; x.u = u << 16; return x.f;
}

// Padded element index: row*72 + col. Affine in row.
__device__ __forceinline__ int sw(int row, int col) {
    return row * LDP + col;
}

// MFMA fragment load: lane l -> row (l&15), k-slice 8*(l>>4); b128 read.
__device__ __forceinline__ s8v frag8(const unsigned short* buf, int row_base, int k_base) {
    const int l = threadIdx.x & 63;
    return *(const s8v*)&buf[sw(row_base + (l & 15), k_base + 8 * (l >> 4))];
}

// ---------------- P0: chunk-local states. Lg: bf16 row-major [i][j] ---------
__global__ __launch_bounds__(256, 4)
void k_p0(const float* __restrict__ kp, const float* __restrict__ vp,
          const float* __restrict__ wp,
          unsigned short* __restrict__ Lg, float* __restrict__ Ag)
{
    __shared__ unsigned short sA[64 * LDP];
    __shared__ unsigned short sVT[64 * LDP];
    __shared__ float spans[4 * 64];          // span DECAYS: prod d over band

    const int blk = blockIdx.x;
    const int g   = blk & (NG - 1);
    const int bh  = blk / NG;
    const int b   = bh / H, h = bh - b * H;
    const int wv  = threadIdx.x >> 6;
    const int ln  = threadIdx.x & 63;

    const int stride = H * N;
    const int base_w = ((b * T + g * TC + wv * 16) * H + h) * N + ln;
    const int cb = (bh * NG + g) * (N * N);

    float d_[16];                            // step decays exp(-exp(w))
    float k_[16];
    {
        float pd = 1.f;
#pragma unroll
        for (int tt = 0; tt < 16; ++tt) {
            const int a = base_w + tt * stride;
            const float dd = __expf(-__expf(wp[a]));
            d_[tt] = dd;
            pd *= dd;
            k_[tt] = kp[a];
        }
        spans[wv * 64 + ln] = pd;            // own band decay
    }
#pragma unroll
    for (int half = 0; half < 2; ++half) {   // V^T: row j=ln, cols t (own band)
        s8v pk;
#pragma unroll
        for (int e = 0; e < 8; ++e)
            pk[e] = (short)cv(vp[base_w + (half * 8 + e) * stride]);
        *(s8v*)&sVT[sw(ln, wv * 16 + half * 8)] = pk;
    }
    __syncthreads();
    const float sd0 = spans[0 * 64 + ln], sd1 = spans[1 * 64 + ln];
    const float sd2 = spans[2 * 64 + ln], sd3 = spans[3 * 64 + ln];
    // decay of all bands AFTER this wave
    const float sfollow = (wv < 1 ? sd1 : 1.f) * (wv < 2 ? sd2 : 1.f)
                        * (wv < 3 ? sd3 : 1.f);

    // K~end^T staging into sA as [i=ln][t]: factor(tt) = suf(tt) * sfollow,
    // suf(tt) = prod d[tt+1..15] — running product, descending.
    s8v p0, p1;
    {
        float suf = sfollow;
#pragma unroll
        for (int tt = 15; tt >= 0; --tt) {
            const unsigned short v16 = cv(k_[tt] * suf);
            if (tt < 8) p0[tt] = (short)v16; else p1[tt - 8] = (short)v16;
            suf *= d_[tt];
        }
    }
    *(s8v*)&sA[sw(ln, wv * 16)]     = p0;
    *(s8v*)&sA[sw(ln, wv * 16 + 8)] = p1;
    __syncthreads();
    // L[i][j] = sum_t KT[i][t] V[t][j]; wave owns i-band
#pragma unroll
    for (int jb = 0; jb < 4; ++jb) {
        f4v acc = {0.f, 0.f, 0.f, 0.f};
        acc = MFMA16(frag8(sA, wv * 16, 0),  frag8(sVT, jb * 16, 0),  acc);
        acc = MFMA16(frag8(sA, wv * 16, 32), frag8(sVT, jb * 16, 32), acc);
        const int i0 = wv * 16 + (ln >> 4) * 4;
        const int j  = jb * 16 + (ln & 15);
#pragma unroll
        for (int q = 0; q < 4; ++q)
            Lg[cb + (i0 + q) * 64 + j] = cv(acc[q]);   // coalesced over ln&15
    }
    if (wv == 0) Ag[(bh * NG + g) * 64 + ln] = sd0 * sd1 * sd2 * sd3;
}

// ---------------- K2: out-of-place scan. L bf16 in -> S0 fp32 out -----------
__global__ __launch_bounds__(256)
void k2_scan(const unsigned short* __restrict__ L, const float* __restrict__ A,
             float* __restrict__ S0)
{
    const int tid = blockIdx.x * 256 + threadIdx.x;   // (bh, i, j2), j2 fastest
    const int j2 = tid & 31;             // uint column (2 bf16 / 1 float2)
    const int i  = (tid >> 5) & 63;
    const int bh = tid >> 11;

    const unsigned* Lu = (const unsigned*)L;
    float2* S2 = (float2*)S0;
    const int lstride = N * N / 2;
    int lidx = (bh * NG) * lstride + i * 32 + j2;
    int aidx = (bh * NG) * N + i;

    float s0 = 0.f, s1 = 0.f;
    for (int g = 0; g < NG; ++g) {
        const unsigned lw = Lu[lidx];
        const float a = A[aidx];
        S2[lidx] = make_float2(s0, s1);  // state at START of chunk g (fp32)
        s0 = fmaf(a, s0, bflo(lw));
        s1 = fmaf(a, s1, bfhi(lw));
        lidx += lstride;
        aidx += N;
    }
}

// ---------------- P1: outputs, CHUNK-PAIRED (c = 0,1 -> chunks 2gp, 2gp+1) --
__global__ __launch_bounds__(256, 2)
void k_p1(const float* __restrict__ rp, const float* __restrict__ kp,
          const float* __restrict__ vp, const float* __restrict__ wp,
          const float* __restrict__ up,
          const float* __restrict__ S0g,   // fp32 chunk-start states [i][j]
          float* __restrict__ out)
{
    __shared__ unsigned short sAb[2][64 * LDP];   // staging A; aliases sAm late
    __shared__ unsigned short sBb[2][64 * LDP];   // staging B
    __shared__ unsigned short sVTb[2][64 * LDP];  // V^T [j][t]
    __shared__ unsigned short sSTb[2][64 * LDP];  // S0^T [j][i]
    __shared__ float spansb[2][4 * 64];           // span DECAYS

    const int blk = blockIdx.x;              // bh*(NG/2) + gp
    const int gp  = blk & (NG / 2 - 1);
    const int bh  = blk / (NG / 2);
    const int b   = bh / H, h = bh - b * H;
    const int wv  = threadIdx.x >> 6;
    const int ln  = threadIdx.x & 63;
    const int cc  = ln & 15;
    const int stride = H * N;

    // ---- prologue for BOTH chunks ------------------------------------------
    float d_[2][16], k_[2][16], r_[2][16];
    int base_w[2], cb[2];
#pragma unroll
    for (int c = 0; c < 2; ++c) {
        const int g = 2 * gp + c;
        base_w[c] = ((b * T + g * TC + wv * 16) * H + h) * N + ln;
        cb[c]     = (bh * NG + g) * (N * N);
        float pd = 1.f;
#pragma unroll
        for (int tt = 0; tt < 16; ++tt) {
            const int a = base_w[c] + tt * stride;
            const float dd = __expf(-__expf(wp[a]));
            d_[c][tt] = dd;
            pd *= dd;
            k_[c][tt] = kp[a];
            r_[c][tt] = rp[a];
        }
        spansb[c][wv * 64 + ln] = pd;
#pragma unroll
        for (int half = 0; half < 2; ++half) {   // V^T: row j=ln, own t-band
            s8v pk;
#pragma unroll
            for (int e = 0; e < 8; ++e)
                pk[e] = (short)cv(vp[base_w[c] + (half * 8 + e) * stride]);
            *(s8v*)&sVTb[c][sw(ln, wv * 16 + half * 8)] = pk;
        }
#pragma unroll
        for (int half = 0; half < 2; ++half) {   // S0^T: row j=ln, cols i
            s8v pk;
#pragma unroll
            for (int e = 0; e < 8; ++e)
                pk[e] = (short)cv(S0g[cb[c] + (wv * 16 + half * 8 + e) * 64 + ln]);
            *(s8v*)&sSTb[c][sw(ln, wv * 16 + half * 8)] = pk;
        }
    }
    __syncthreads();

    float dOffW[2], sd1v[2], sd2v[2];
#pragma unroll
    for (int c = 0; c < 2; ++c) {
        const float sd0 = spansb[c][0 * 64 + ln];
        const float sd1 = spansb[c][1 * 64 + ln];
        const float sd2 = spansb[c][2 * 64 + ln];
        dOffW[c] = (wv > 0 ? sd0 : 1.f) * (wv > 1 ? sd1 : 1.f)
                 * (wv > 2 ? sd2 : 1.f);
        sd1v[c] = sd1;
        sd2v[c] = sd2;
    }
    const float uln = up[h * 64 + ln];

    // ---- diag: level 0 (plain r x plain k), both chunks --------------------
    f4v accD[2] = {{0.f, 0.f, 0.f, 0.f}, {0.f, 0.f, 0.f, 0.f}};
#pragma unroll
    for (int c = 0; c < 2; ++c) {
#pragma unroll
        for (int tt = 0; tt < 16; ++tt) sBb[c][sw(wv * 16 + tt, ln)] = cv(k_[c][tt]);
#pragma unroll
        for (int tt = 0; tt < 16; ++tt) sAb[c][sw(wv * 16 + tt, ln)] = cv(r_[c][tt]);
    }
#pragma unroll
    for (int c = 0; c < 2; ++c) {
        f4v tmp = {0.f, 0.f, 0.f, 0.f};
        tmp = MFMA16(frag8(sAb[c], wv * 16, 0),  frag8(sBb[c], wv * 16, 0),  tmp);
        tmp = MFMA16(frag8(sAb[c], wv * 16, 32), frag8(sBb[c], wv * 16, 32), tmp);
#pragma unroll
        for (int q = 0; q < 4; ++q) {
            const int tt = (ln >> 4) * 4 + q;
            if (tt == cc + 1 && (tt & 1)) accD[c][q] += tmp[q];
        }
    }
    // ---- u-diag: A = r*u, same plain-k B; mask t==s ------------------------
#pragma unroll
    for (int c = 0; c < 2; ++c) {
#pragma unroll
        for (int tt = 0; tt < 16; ++tt)
            sAb[c][sw(wv * 16 + tt, ln)] = cv(r_[c][tt] * uln);
    }
#pragma unroll
    for (int c = 0; c < 2; ++c) {
        f4v tmp = {0.f, 0.f, 0.f, 0.f};
        tmp = MFMA16(frag8(sAb[c], wv * 16, 0),  frag8(sBb[c], wv * 16, 0),  tmp);
        tmp = MFMA16(frag8(sAb[c], wv * 16, 32), frag8(sBb[c], wv * 16, 32), tmp);
#pragma unroll
        for (int q = 0; q < 4; ++q) {
            const int tt = (ln >> 4) * 4 + q;
            if (tt == cc) accD[c][q] += tmp[q];
        }
    }
    // ---- levels 1..3: masked dyadic pairs, both chunks ---------------------
#pragma unroll
    for (int L = 1; L < 4; ++L) {
#pragma unroll
        for (int c = 0; c < 2; ++c) {
            float fA = 1.f;
#pragma unroll
            for (int tt = 0; tt < 16; ++tt) {
                if ((tt & ((1 << L) - 1)) == 0) fA = 1.f;
                else                            fA *= d_[c][tt - 1];
                sAb[c][sw(wv * 16 + tt, ln)] = cv(r_[c][tt] * fA);
            }
            float fB = 1.f;
#pragma unroll
            for (int tt = 15; tt >= 0; --tt) {
                if ((tt & ((1 << L) - 1)) == ((1 << L) - 1)) fB = 1.f;
                else                                         fB *= d_[c][tt + 1];
                sBb[c][sw(wv * 16 + tt, ln)] = cv(k_[c][tt] * fB);
            }
        }
#pragma unroll
        for (int c = 0; c < 2; ++c) {
            f4v tmp = {0.f, 0.f, 0.f, 0.f};
            tmp = MFMA16(frag8(sAb[c], wv * 16, 0),  frag8(sBb[c], wv * 16, 0),  tmp);
            tmp = MFMA16(frag8(sAb[c], wv * 16, 32), frag8(sBb[c], wv * 16, 32), tmp);
#pragma unroll
            for (int q = 0; q < 4; ++q) {
                const int tt = (ln >> 4) * 4 + q;
                if (((tt >> L) == ((cc >> L) + 1)) && (((tt >> L) & 1) != 0))
                    accD[c][q] += tmp[q];
            }
        }
    }

    // ---- level 4: whole tiles (1,0),(3,2); band prefix/suffix products -----
#pragma unroll
    for (int c = 0; c < 2; ++c) {
        float pfx = 1.f;
#pragma unroll
        for (int tt = 0; tt < 16; ++tt) {
            sAb[c][sw(wv * 16 + tt, ln)] = cv(r_[c][tt] * pfx);
            pfx *= d_[c][tt];
        }
        float suf = 1.f;
#pragma unroll
        for (int tt = 15; tt >= 0; --tt) {
            sBb[c][sw(wv * 16 + tt, ln)] = cv(k_[c][tt] * suf);
            suf *= d_[c][tt];
        }
    }
    __syncthreads();
    f4v accL4[2] = {{0.f, 0.f, 0.f, 0.f}, {0.f, 0.f, 0.f, 0.f}};
    if (wv == 1 || wv == 3) {
#pragma unroll
        for (int c = 0; c < 2; ++c) {
            accL4[c] = MFMA16(frag8(sAb[c], wv * 16, 0),
                              frag8(sBb[c], (wv - 1) * 16, 0),  accL4[c]);
            accL4[c] = MFMA16(frag8(sAb[c], wv * 16, 32),
                              frag8(sBb[c], (wv - 1) * 16, 32), accL4[c]);
        }
    }
    __syncthreads();   // cross-band sB reads done before L5 prep overwrites

    // ---- level 5: tiles (2,0),(2,1),(3,0),(3,1); refs at chunk-mid ---------
#pragma unroll
    for (int c = 0; c < 2; ++c) {
        if (wv >= 2) {
            float f = (wv == 2) ? 1.f : sd2v[c];   // A: pfx (* sd2 for wv3)
#pragma unroll
            for (int tt = 0; tt < 16; ++tt) {
                sAb[c][sw(wv * 16 + tt, ln)] = cv(r_[c][tt] * f);
                f *= d_[c][tt];
            }
        } else {
            float f = (wv == 0) ? sd1v[c] : 1.f;   // B: suf (* sd1 for wv0)
#pragma unroll
            for (int tt = 15; tt >= 0; --tt) {
                sBb[c][sw(wv * 16 + tt, ln)] = cv(k_[c][tt] * f);
                f *= d_[c][tt];
            }
        }
    }
    __syncthreads();
    f4v acc50[2] = {{0.f, 0.f, 0.f, 0.f}, {0.f, 0.f, 0.f, 0.f}};
    f4v acc51[2] = {{0.f, 0.f, 0.f, 0.f}, {0.f, 0.f, 0.f, 0.f}};
    if (wv >= 2) {
#pragma unroll
        for (int c = 0; c < 2; ++c) {
            acc50[c] = MFMA16(frag8(sAb[c], wv * 16, 0),  frag8(sBb[c], 0, 0),   acc50[c]);
            acc50[c] = MFMA16(frag8(sAb[c], wv * 16, 32), frag8(sBb[c], 0, 32),  acc50[c]);
            acc51[c] = MFMA16(frag8(sAb[c], wv * 16, 0),  frag8(sBb[c], 16, 0),  acc51[c]);
            acc51[c] = MFMA16(frag8(sAb[c], wv * 16, 32), frag8(sBb[c], 16, 32), acc51[c]);
        }
    }
    // (no barrier: epilogue writes only own sA rows after own-row reads,
    //  wave-in-order; sST/sVT are prologue-staged and never overwritten)

    // ---- epilogue, per chunk (accO short-lived — R8 rule) ------------------
#pragma unroll
    for (int c = 0; c < 2; ++c) {
        // R~0 prep: factor = dOffW * pfx[tt]
        {
            float f = dOffW[c];
#pragma unroll
            for (int tt = 0; tt < 16; ++tt) {
                sAb[c][sw(wv * 16 + tt, ln)] = cv(r_[c][tt] * f);
                f *= d_[c][tt];
            }
        }
        f4v accO[4];
#pragma unroll
        for (int jb = 0; jb < 4; ++jb) {
            f4v a = {0.f, 0.f, 0.f, 0.f};
            a = MFMA16(frag8(sAb[c], wv * 16, 0),  frag8(sSTb[c], jb * 16, 0),  a);
            a = MFMA16(frag8(sAb[c], wv * 16, 32), frag8(sSTb[c], jb * 16, 32), a);
            accO[jb] = a;
        }

        // materialize A into sAm (= sAb[c] alias): own-band rows only
        unsigned short* const sAm = sAb[c];
#pragma unroll
        for (int q = 0; q < 4; ++q) {
            const int tt = (ln >> 4) * 4 + q;
            sAm[sw(wv * 16 + tt, wv * 16 + cc)] = cv(accD[c][q]);
        }
        if (wv == 1 || wv == 3) {
#pragma unroll
            for (int q = 0; q < 4; ++q) {
                const int tt = (ln >> 4) * 4 + q;
                sAm[sw(wv * 16 + tt, (wv - 1) * 16 + cc)] = cv(accL4[c][q]);
            }
        }
        if (wv >= 2) {
#pragma unroll
            for (int q = 0; q < 4; ++q) {
                const int tt = (ln >> 4) * 4 + q;
                sAm[sw(wv * 16 + tt, cc)]      = cv(acc50[c][q]);
                sAm[sw(wv * 16 + tt, 16 + cc)] = cv(acc51[c][q]);
            }
        }
        if (wv == 0 || wv == 2) {    // zero upper-adjacent tile for K32 pairing
#pragma unroll
            for (int q = 0; q < 4; ++q) {
                const int tt = (ln >> 4) * 4 + q;
                sAm[sw(wv * 16 + tt, (wv + 1) * 16 + cc)] = 0;
            }
        }

        // out = accO + A @ V
#pragma unroll
        for (int jb = 0; jb < 4; ++jb) {
            f4v a = accO[jb];
            a = MFMA16(frag8(sAm, wv * 16, 0), frag8(sVTb[c], jb * 16, 0), a);
            if (wv >= 2)
                a = MFMA16(frag8(sAm, wv * 16, 32), frag8(sVTb[c], jb * 16, 32), a);
#pragma unroll
            for (int q = 0; q < 4; ++q) {
                const int t = (2 * gp + c) * TC + wv * 16 + (ln >> 4) * 4 + q;
                out[((b * T + t) * H + h) * N + jb * 16 + (ln & 15)] = a[q];
            }
        }
    }
}

// ---------------- no-workspace fallback: sequential per (b,h) ---------------
__global__ __launch_bounds__(64, 2)
void k_seq(const float* __restrict__ rp, const float* __restrict__ kp,
           const float* __restrict__ vp, const float* __restrict__ wp,
           const float* __restrict__ up, float* __restrict__ out)
{
    const int bh = blockIdx.x;
    const int b = bh / H, h = bh - b * H;
    const int j = threadIdx.x;

    float S[N];
#pragma unroll
    for (int i = 0; i < N; ++i) S[i] = 0.f;

    const int stride = H * N;
    int base = ((b * T) * H + h) * N;
    const int ubase = h * N;

#pragma unroll 1
    for (int tt = 0; tt < T; ++tt) {
        const float vj = vp[base + j];
        const int row = base;
        float sr = 0.f, o0 = 0.f, o1 = 0.f;
#pragma unroll
        for (int i = 0; i < N; ++i) {
            const float ki = kp[row + i];
            const float di = __expf(-__expf(wp[row + i]));
            const float ri = rp[row + i];
            sr = fmaf(ri * up[ubase + i], ki, sr);
            if (i & 1) o1 = fmaf(ri, S[i], o1);
            else       o0 = fmaf(ri, S[i], o0);
            S[i] = fmaf(di, S[i], ki * vj);
        }
        out[base + j] = fmaf(sr, vj, o0 + o1);
        base += stride;
    }
}

} // anon namespace

extern "C" void kernel_launch(void* const* d_in, const int* in_sizes, int n_in,
                              void* d_out, int out_size, void* d_ws, size_t ws_size,
                              hipStream_t stream)
{
    const float* r = (const float*)d_in[0];
    const float* k = (const float*)d_in[1];
    const float* v = (const float*)d_in[2];
    const float* w = (const float*)d_in[3];
    const float* u = (const float*)d_in[4];
    float* out = (float*)d_out;

    const size_t l_elems = (size_t)BH * NG * N * N;   // 8,388,608
    const size_t a_elems = (size_t)BH * NG * N;       // 131,072
    // L bf16 (16.8MB) + A fp32 (0.5MB) + S0 fp32 (33.6MB) = ~50.9MB
    const size_t ws_need = l_elems * sizeof(unsigned short)
                         + a_elems * sizeof(float)
                         + l_elems * sizeof(float);

    if (ws_size >= ws_need) {
        unsigned short* L = (unsigned short*)d_ws;
        float* A  = (float*)(L + l_elems);
        float* S0 = A + a_elems;
        k_p0<<<BH * NG, 256, 0, stream>>>(k, v, w, L, A);
        k2_scan<<<(BH * N * N / 2) / 256, 256, 0, stream>>>(L, A, S0);
        k_p1<<<BH * NG / 2, 256, 0, stream>>>(r, k, v, w, u, S0, out);
    } else {
        k_seq<<<BH, 64, 0, stream>>>(r, k, v, w, u, out);
    }
}

// Round 23
// 66.875 us; speedup vs baseline: 1.1609x; 1.1609x over previous
//
#include <hip/hip_runtime.h>
#include <math.h>

// RWKV-6 fused recurrent WKV — chunked linear scan, MFMA formulation.
// FINAL (= R19/R21, best measured variant: 67.5-67.8us, reproduced twice).
// B=4, T=2048, H=16, N=64, fp32 in/out; bf16 MFMA operands, fp32 accum.
//
// Chunk TC=64 per workgroup (bh,g), 4 waves, wave w owns t-band [16w,16w+16).
// A[t,s] = sum_i r_t,i k_s,i exp(-(c[t-1]-c[s])), c = incl. prefix of exp(w).
// Dyadic-safe factorization (all staged factors <= 1). Levels 0-3 + u-diag
// inside 16x16 diag tiles (masked accum); L4: tiles (1,0),(3,2); L5: (2,*),
// (3,0),(3,1). o = R~0 @ S0 + A @ V;  L_g = K~end^T @ V -> K2 scan.
//
// Session ledger:
// R8: never trade register live-range for LDS (accO stays last).
// R9: __float2bfloat16 tips regalloc into spill; manual RNE is stable.
// R11-R14 (NaN): partial sST staging / union-punning — excluded for good.
// R15: L/S0 layout must serve the consumer's lane pattern.
// R16: P0 bf16-L write + packed k2 proven (-9us).
// R17: long-lived prefetch regs -> spill. Reverted.
// R18: compose R10-P1 (fp32 S0, separate sST, prologue staging) + bf16-L P0
//   + out-of-place k2 = 70.8us.
// R19: 176 expf -> 32 expf + running decay products = 67.8us (P1 40.6).
// R20: occupancy/late-staging isolating experiment: null (P1 40.1, total
//   68.8 slightly worse). Reverted.
// R22: chunk-paired P1 (in-wave ILP, (256,2), 75.8KB LDS): P1 49-51us —
//   ILP < TLP for these chains (VALUBusy 32->25%, occ 30->16.7%). Reverted.
// P1 ~40.6us is structural to the 13-phase staged-GEMM form: no pipe >36%,
// all mechanistic axes (VALU, occupancy, staging position, ILP) tested.

namespace {
constexpr int B = 4, T = 2048, H = 16, N = 64;
constexpr int BH = B * H;
constexpr int NG = 32;           // chunks per (b,h)
constexpr int TC = 64;           // steps per chunk
constexpr int LDP = 72;          // LDS row stride (elems): 144B, 16B-aligned

typedef __attribute__((ext_vector_type(8))) short s8v;   // 8 bf16
typedef __attribute__((ext_vector_type(4))) float f4v;

#define MFMA16(a, b, c) __builtin_amdgcn_mfma_f32_16x16x32_bf16((a), (b), (c), 0, 0, 0)

__device__ __forceinline__ unsigned short cv(float f) {
    union { float f; unsigned u; } x; x.f = f;
    unsigned r = x.u + 0x7FFFu + ((x.u >> 16) & 1u);   // branchless RNE
    return (unsigned short)(r >> 16);
}

__device__ __forceinline__ float bfhi(unsigned u) {   // upper bf16 -> float
    union { unsigned u; float f; } x; x.u = u & 0xFFFF0000u; return x.f;
}
__device__ __forceinline__ float bflo(unsigned u) {   // lower bf16 -> float
    union { unsigned u; float f; } x; x.u = u << 16; return x.f;
}

// Padded element index: row*72 + col. Affine in row.
__device__ __forceinline__ int sw(int row, int col) {
    return row * LDP + col;
}

// MFMA fragment load: lane l -> row (l&15), k-slice 8*(l>>4); b128 read.
__device__ __forceinline__ s8v frag8(const unsigned short* buf, int row_base, int k_base) {
    const int l = threadIdx.x & 63;
    return *(const s8v*)&buf[sw(row_base + (l & 15), k_base + 8 * (l >> 4))];
}

// ---------------- P0: chunk-local states. Lg: bf16 row-major [i][j] ---------
__global__ __launch_bounds__(256, 4)
void k_p0(const float* __restrict__ kp, const float* __restrict__ vp,
          const float* __restrict__ wp,
          unsigned short* __restrict__ Lg, float* __restrict__ Ag)
{
    __shared__ unsigned short sA[64 * LDP];
    __shared__ unsigned short sVT[64 * LDP];
    __shared__ float spans[4 * 64];          // span DECAYS: prod d over band

    const int blk = blockIdx.x;
    const int g   = blk & (NG - 1);
    const int bh  = blk / NG;
    const int b   = bh / H, h = bh - b * H;
    const int wv  = threadIdx.x >> 6;
    const int ln  = threadIdx.x & 63;

    const int stride = H * N;
    const int base_w = ((b * T + g * TC + wv * 16) * H + h) * N + ln;
    const int cb = (bh * NG + g) * (N * N);

    float d_[16];                            // step decays exp(-exp(w))
    float k_[16];
    {
        float pd = 1.f;
#pragma unroll
        for (int tt = 0; tt < 16; ++tt) {
            const int a = base_w + tt * stride;
            const float dd = __expf(-__expf(wp[a]));
            d_[tt] = dd;
            pd *= dd;
            k_[tt] = kp[a];
        }
        spans[wv * 64 + ln] = pd;            // own band decay
    }
#pragma unroll
    for (int half = 0; half < 2; ++half) {   // V^T: row j=ln, cols t (own band)
        s8v pk;
#pragma unroll
        for (int e = 0; e < 8; ++e)
            pk[e] = (short)cv(vp[base_w + (half * 8 + e) * stride]);
        *(s8v*)&sVT[sw(ln, wv * 16 + half * 8)] = pk;
    }
    __syncthreads();
    const float sd0 = spans[0 * 64 + ln], sd1 = spans[1 * 64 + ln];
    const float sd2 = spans[2 * 64 + ln], sd3 = spans[3 * 64 + ln];
    // decay of all bands AFTER this wave
    const float sfollow = (wv < 1 ? sd1 : 1.f) * (wv < 2 ? sd2 : 1.f)
                        * (wv < 3 ? sd3 : 1.f);

    // K~end^T staging into sA as [i=ln][t]: factor(tt) = suf(tt) * sfollow,
    // suf(tt) = prod d[tt+1..15] — running product, descending.
    s8v p0, p1;
    {
        float suf = sfollow;
#pragma unroll
        for (int tt = 15; tt >= 0; --tt) {
            const unsigned short v16 = cv(k_[tt] * suf);
            if (tt < 8) p0[tt] = (short)v16; else p1[tt - 8] = (short)v16;
            suf *= d_[tt];
        }
    }
    *(s8v*)&sA[sw(ln, wv * 16)]     = p0;
    *(s8v*)&sA[sw(ln, wv * 16 + 8)] = p1;
    __syncthreads();
    // L[i][j] = sum_t KT[i][t] V[t][j]; wave owns i-band
#pragma unroll
    for (int jb = 0; jb < 4; ++jb) {
        f4v acc = {0.f, 0.f, 0.f, 0.f};
        acc = MFMA16(frag8(sA, wv * 16, 0),  frag8(sVT, jb * 16, 0),  acc);
        acc = MFMA16(frag8(sA, wv * 16, 32), frag8(sVT, jb * 16, 32), acc);
        const int i0 = wv * 16 + (ln >> 4) * 4;
        const int j  = jb * 16 + (ln & 15);
#pragma unroll
        for (int q = 0; q < 4; ++q)
            Lg[cb + (i0 + q) * 64 + j] = cv(acc[q]);   // coalesced over ln&15
    }
    if (wv == 0) Ag[(bh * NG + g) * 64 + ln] = sd0 * sd1 * sd2 * sd3;
}

// ---------------- K2: out-of-place scan. L bf16 in -> S0 fp32 out -----------
__global__ __launch_bounds__(256)
void k2_scan(const unsigned short* __restrict__ L, const float* __restrict__ A,
             float* __restrict__ S0)
{
    const int tid = blockIdx.x * 256 + threadIdx.x;   // (bh, i, j2), j2 fastest
    const int j2 = tid & 31;             // uint column (2 bf16 / 1 float2)
    const int i  = (tid >> 5) & 63;
    const int bh = tid >> 11;

    const unsigned* Lu = (const unsigned*)L;
    float2* S2 = (float2*)S0;
    const int lstride = N * N / 2;
    int lidx = (bh * NG) * lstride + i * 32 + j2;
    int aidx = (bh * NG) * N + i;

    float s0 = 0.f, s1 = 0.f;
    for (int g = 0; g < NG; ++g) {
        const unsigned lw = Lu[lidx];
        const float a = A[aidx];
        S2[lidx] = make_float2(s0, s1);  // state at START of chunk g (fp32)
        s0 = fmaf(a, s0, bflo(lw));
        s1 = fmaf(a, s1, bfhi(lw));
        lidx += lstride;
        aidx += N;
    }
}

// ---------------- P1: outputs (R18 structure; factors via decay products) ---
__global__ __launch_bounds__(256, 4)
void k_p1(const float* __restrict__ rp, const float* __restrict__ kp,
          const float* __restrict__ vp, const float* __restrict__ wp,
          const float* __restrict__ up,
          const float* __restrict__ S0g,   // fp32 chunk-start states [i][j]
          float* __restrict__ out)
{
    __shared__ unsigned short sA[64 * LDP];   // staging A-op; aliases sAm (late)
    __shared__ unsigned short sB[64 * LDP];   // staging B-op
    __shared__ unsigned short sVT[64 * LDP];  // V transposed [j][t]
    __shared__ unsigned short sST[64 * LDP];  // S0^T [j][i] — separate buffer
    __shared__ float spans[4 * 64];           // span DECAYS
    unsigned short* const sAm = sA;

    const int blk = blockIdx.x;
    const int g   = blk & (NG - 1);
    const int bh  = blk / NG;
    const int b   = bh / H, h = bh - b * H;
    const int wv  = threadIdx.x >> 6;
    const int ln  = threadIdx.x & 63;

    const int stride = H * N;
    const int base_w = ((b * T + g * TC + wv * 16) * H + h) * N + ln;
    const int cb = (bh * NG + g) * (N * N);

    // ---- prologue: rows, step decays, stage V^T and S0^T -------------------
    float d_[16];
    float k_[16], r_[16];
    {
        float pd = 1.f;
#pragma unroll
        for (int tt = 0; tt < 16; ++tt) {
            const int a = base_w + tt * stride;
            const float dd = __expf(-__expf(wp[a]));
            d_[tt] = dd;
            pd *= dd;
            k_[tt] = kp[a];
            r_[tt] = rp[a];
        }
        spans[wv * 64 + ln] = pd;
    }
#pragma unroll
    for (int half = 0; half < 2; ++half) {   // V^T: row j=ln, cols t (own band)
        s8v pk;
#pragma unroll
        for (int e = 0; e < 8; ++e)
            pk[e] = (short)cv(vp[base_w + (half * 8 + e) * stride]);
        *(s8v*)&sVT[sw(ln, wv * 16 + half * 8)] = pk;
    }
#pragma unroll
    for (int half = 0; half < 2; ++half) {   // S0^T: row j=ln, cols i (fp32 in)
        s8v pk;
#pragma unroll
        for (int e = 0; e < 8; ++e)
            pk[e] = (short)cv(S0g[cb + (wv * 16 + half * 8 + e) * 64 + ln]);
        *(s8v*)&sST[sw(ln, wv * 16 + half * 8)] = pk;
    }
    __syncthreads();
    const float sd0 = spans[0 * 64 + ln], sd1 = spans[1 * 64 + ln];
    const float sd2 = spans[2 * 64 + ln];
    // decay of all bands BEFORE this wave (chunk start -> band start)
    const float dOffW = (wv > 0 ? sd0 : 1.f) * (wv > 1 ? sd1 : 1.f)
                      * (wv > 2 ? sd2 : 1.f);

    const float uln = up[h * 64 + ln];
    const int cc = ln & 15;

    // ---- diag tile (wv,wv): shared plain-k B; level 0 + u-diag + levels 1-3
    f4v accD = {0.f, 0.f, 0.f, 0.f};
#pragma unroll
    for (int tt = 0; tt < 16; ++tt) sB[sw(wv * 16 + tt, ln)] = cv(k_[tt]);
#pragma unroll
    for (int tt = 0; tt < 16; ++tt) sA[sw(wv * 16 + tt, ln)] = cv(r_[tt]);
    {
        f4v tmp = {0.f, 0.f, 0.f, 0.f};
        tmp = MFMA16(frag8(sA, wv * 16, 0),  frag8(sB, wv * 16, 0),  tmp);
        tmp = MFMA16(frag8(sA, wv * 16, 32), frag8(sB, wv * 16, 32), tmp);
#pragma unroll
        for (int q = 0; q < 4; ++q) {
            const int tt = (ln >> 4) * 4 + q;
            if (tt == cc + 1 && (tt & 1)) accD[q] += tmp[q];
        }
    }
#pragma unroll
    for (int tt = 0; tt < 16; ++tt) sA[sw(wv * 16 + tt, ln)] = cv(r_[tt] * uln);
    {
        f4v tmp = {0.f, 0.f, 0.f, 0.f};
        tmp = MFMA16(frag8(sA, wv * 16, 0),  frag8(sB, wv * 16, 0),  tmp);
        tmp = MFMA16(frag8(sA, wv * 16, 32), frag8(sB, wv * 16, 32), tmp);
#pragma unroll
        for (int q = 0; q < 4; ++q) {
            const int tt = (ln >> 4) * 4 + q;
            if (tt == cc) accD[q] += tmp[q];
        }
    }
    // levels 1..3: masked dyadic pairs; factors = block-local running products
#pragma unroll
    for (int L = 1; L < 4; ++L) {
        {   // A: factor(tt) = prod d[btl..tt-1]; ascending, reset at block start
            float fA = 1.f;
#pragma unroll
            for (int tt = 0; tt < 16; ++tt) {
                if ((tt & ((1 << L) - 1)) == 0) fA = 1.f;
                else                            fA *= d_[tt - 1];
                sA[sw(wv * 16 + tt, ln)] = cv(r_[tt] * fA);
            }
        }
        {   // B: factor(tt) = prod d[tt+1..bsl-1]; descending, reset at block end
            float fB = 1.f;
#pragma unroll
            for (int tt = 15; tt >= 0; --tt) {
                if ((tt & ((1 << L) - 1)) == ((1 << L) - 1)) fB = 1.f;
                else                                         fB *= d_[tt + 1];
                sB[sw(wv * 16 + tt, ln)] = cv(k_[tt] * fB);
            }
        }
        f4v tmp = {0.f, 0.f, 0.f, 0.f};
        tmp = MFMA16(frag8(sA, wv * 16, 0),  frag8(sB, wv * 16, 0),  tmp);
        tmp = MFMA16(frag8(sA, wv * 16, 32), frag8(sB, wv * 16, 32), tmp);
#pragma unroll
        for (int q = 0; q < 4; ++q) {
            const int tt = (ln >> 4) * 4 + q;
            if (((tt >> L) == ((cc >> L) + 1)) && (((tt >> L) & 1) != 0))
                accD[q] += tmp[q];
        }
    }

    // ---- level 4: whole tiles (1,0),(3,2); band prefix/suffix products -----
    {
        float pfx = 1.f;                       // A: prod d[0..tt-1]
#pragma unroll
        for (int tt = 0; tt < 16; ++tt) {
            sA[sw(wv * 16 + tt, ln)] = cv(r_[tt] * pfx);
            pfx *= d_[tt];
        }
        float suf = 1.f;                       // B: prod d[tt+1..15]
#pragma unroll
        for (int tt = 15; tt >= 0; --tt) {
            sB[sw(wv * 16 + tt, ln)] = cv(k_[tt] * suf);
            suf *= d_[tt];
        }
    }
    __syncthreads();
    f4v accL4 = {0.f, 0.f, 0.f, 0.f};
    if (wv == 1 || wv == 3) {
        accL4 = MFMA16(frag8(sA, wv * 16, 0),  frag8(sB, (wv - 1) * 16, 0),  accL4);
        accL4 = MFMA16(frag8(sA, wv * 16, 32), frag8(sB, (wv - 1) * 16, 32), accL4);
    }
    __syncthreads();   // cross-band sB reads done before L5 prep overwrites

    // ---- level 5: tiles (2,0),(2,1),(3,0),(3,1); refs at chunk-mid ---------
    if (wv >= 2) {
        float f = (wv == 2) ? 1.f : sd2;       // A: pfx[tt] (* sd2 for wv3)
#pragma unroll
        for (int tt = 0; tt < 16; ++tt) {
            sA[sw(wv * 16 + tt, ln)] = cv(r_[tt] * f);
            f *= d_[tt];
        }
    } else {
        float f = (wv == 0) ? sd1 : 1.f;       // B: suf[tt] (* sd1 for wv0)
#pragma unroll
        for (int tt = 15; tt >= 0; --tt) {
            sB[sw(wv * 16 + tt, ln)] = cv(k_[tt] * f);
            f *= d_[tt];
        }
    }
    __syncthreads();
    f4v acc50 = {0.f, 0.f, 0.f, 0.f}, acc51 = {0.f, 0.f, 0.f, 0.f};
    if (wv >= 2) {
        acc50 = MFMA16(frag8(sA, wv * 16, 0),  frag8(sB, 0, 0),   acc50);
        acc50 = MFMA16(frag8(sA, wv * 16, 32), frag8(sB, 0, 32),  acc50);
        acc51 = MFMA16(frag8(sA, wv * 16, 0),  frag8(sB, 16, 0),  acc51);
        acc51 = MFMA16(frag8(sA, wv * 16, 32), frag8(sB, 16, 32), acc51);
    }
    // (no barrier: R~0 prep writes only own sA rows; L5 GEMM reads own sA
    //  rows in-order and sB bands 0/1, which are not rewritten)

    // ---- R~0 (chunk-start ref): factor = dOffW * pfx[tt] -------------------
    {
        float f = dOffW;
#pragma unroll
        for (int tt = 0; tt < 16; ++tt) {
            sA[sw(wv * 16 + tt, ln)] = cv(r_[tt] * f);
            f *= d_[tt];
        }
    }
    f4v accO[4];
#pragma unroll
    for (int jb = 0; jb < 4; ++jb) {
        f4v a = {0.f, 0.f, 0.f, 0.f};
        a = MFMA16(frag8(sA, wv * 16, 0),  frag8(sST, jb * 16, 0),  a);
        a = MFMA16(frag8(sA, wv * 16, 32), frag8(sST, jb * 16, 32), a);
        accO[jb] = a;
    }

    // ---- materialize A into sAm (=sA alias): own-band rows only ------------
#pragma unroll
    for (int q = 0; q < 4; ++q) {
        const int tt = (ln >> 4) * 4 + q;
        sAm[sw(wv * 16 + tt, wv * 16 + cc)] = cv(accD[q]);
    }
    if (wv == 1 || wv == 3) {
#pragma unroll
        for (int q = 0; q < 4; ++q) {
            const int tt = (ln >> 4) * 4 + q;
            sAm[sw(wv * 16 + tt, (wv - 1) * 16 + cc)] = cv(accL4[q]);
        }
    }
    if (wv >= 2) {
#pragma unroll
        for (int q = 0; q < 4; ++q) {
            const int tt = (ln >> 4) * 4 + q;
            sAm[sw(wv * 16 + tt, cc)]      = cv(acc50[q]);
            sAm[sw(wv * 16 + tt, 16 + cc)] = cv(acc51[q]);
        }
    }
    if (wv == 0 || wv == 2) {    // zero upper-adjacent tile for K32 pairing
#pragma unroll
        for (int q = 0; q < 4; ++q) {
            const int tt = (ln >> 4) * 4 + q;
            sAm[sw(wv * 16 + tt, (wv + 1) * 16 + cc)] = 0;
        }
    }

    // ---- out = accO + A @ V ------------------------------------------------
#pragma unroll
    for (int jb = 0; jb < 4; ++jb) {
        f4v a = accO[jb];
        a = MFMA16(frag8(sAm, wv * 16, 0), frag8(sVT, jb * 16, 0), a);
        if (wv >= 2)
            a = MFMA16(frag8(sAm, wv * 16, 32), frag8(sVT, jb * 16, 32), a);
#pragma unroll
        for (int q = 0; q < 4; ++q) {
            const int t = g * TC + wv * 16 + (ln >> 4) * 4 + q;
            out[((b * T + t) * H + h) * N + jb * 16 + (ln & 15)] = a[q];
        }
    }
}

// ---------------- no-workspace fallback: sequential per (b,h) ---------------
__global__ __launch_bounds__(64, 2)
void k_seq(const float* __restrict__ rp, const float* __restrict__ kp,
           const float* __restrict__ vp, const float* __restrict__ wp,
           const float* __restrict__ up, float* __restrict__ out)
{
    const int bh = blockIdx.x;
    const int b = bh / H, h = bh - b * H;
    const int j = threadIdx.x;

    float S[N];
#pragma unroll
    for (int i = 0; i < N; ++i) S[i] = 0.f;

    const int stride = H * N;
    int base = ((b * T) * H + h) * N;
    const int ubase = h * N;

#pragma unroll 1
    for (int tt = 0; tt < T; ++tt) {
        const float vj = vp[base + j];
        const int row = base;
        float sr = 0.f, o0 = 0.f, o1 = 0.f;
#pragma unroll
        for (int i = 0; i < N; ++i) {
            const float ki = kp[row + i];
            const float di = __expf(-__expf(wp[row + i]));
            const float ri = rp[row + i];
            sr = fmaf(ri * up[ubase + i], ki, sr);
            if (i & 1) o1 = fmaf(ri, S[i], o1);
            else       o0 = fmaf(ri, S[i], o0);
            S[i] = fmaf(di, S[i], ki * vj);
        }
        out[base + j] = fmaf(sr, vj, o0 + o1);
        base += stride;
    }
}

} // anon namespace

extern "C" void kernel_launch(void* const* d_in, const int* in_sizes, int n_in,
                              void* d_out, int out_size, void* d_ws, size_t ws_size,
                              hipStream_t stream)
{
    const float* r = (const float*)d_in[0];
    const float* k = (const float*)d_in[1];
    const float* v = (const float*)d_in[2];
    const float* w = (const float*)d_in[3];
    const float* u = (const float*)d_in[4];
    float* out = (float*)d_out;

    const size_t l_elems = (size_t)BH * NG * N * N;   // 8,388,608
    const size_t a_elems = (size_t)BH * NG * N;       // 131,072
    // L bf16 (16.8MB) + A fp32 (0.5MB) + S0 fp32 (33.6MB) = ~50.9MB
    const size_t ws_need = l_elems * sizeof(unsigned short)
                         + a_elems * sizeof(float)
                         + l_elems * sizeof(float);

    if (ws_size >= ws_need) {
        unsigned short* L = (unsigned short*)d_ws;
        float* A  = (float*)(L + l_elems);
        float* S0 = A + a_elems;
        k_p0<<<BH * NG, 256, 0, stream>>>(k, v, w, L, A);
        k2_scan<<<(BH * N * N / 2) / 256, 256, 0, stream>>>(L, A, S0);
        k_p1<<<BH * NG, 256, 0, stream>>>(r, k, v, w, u, S0, out);
    } else {
        k_seq<<<BH, 64, 0, stream>>>(r, k, v, w, u, out);
    }
}